// Round 18
// baseline (215.302 us; speedup 1.0000x reference)
//
#include <hip/hip_runtime.h>
#include <hip/hip_fp16.h>

#define NN 50000
#define NE 800000
#define D  128
#define NC 40
#define NBLK ((NN + 255) / 256)
#define NXCD 8
#define DRANGE ((NN + NXCD - 1) / NXCD)   // 6250
#define EPB 2048
#define NCH ((NE + EPB - 1) / EPB)        // 391
#define CAP 64                             // bucket capacity (Poisson(16): P(>64)~1e-19)
#define NTILE ((NN + 127) / 128)           // 391 gemm tiles
#define CSTR 16                            // cnt stride (ints): 1 counter per 64B line
#define NZB ((NN * CSTR / 4 + 127) / 128)  // int4-zero blocks for cnt

typedef short bf16x8 __attribute__((ext_vector_type(8)));
typedef float f32x16 __attribute__((ext_vector_type(16)));

// ---------- edge loading (int32/int64 auto-detect) ----------
__device__ __forceinline__ void load_edge(const void* ei, int e, int is64, int& s, int& d) {
    if (is64) {
        const long long* p = (const long long*)ei;
        s = (int)p[e]; d = (int)p[NE + e];
    } else {
        const int* p = (const int*)ei;
        s = p[e]; d = p[NE + e];
    }
}

// ---------- bf16 split helpers ----------
__device__ __forceinline__ ushort f2bf(float x) {
    unsigned u = __float_as_uint(x);
    return (ushort)((u + 0x7fffu + ((u >> 16) & 1u)) >> 16);
}
__device__ __forceinline__ float bf2f(ushort h) {
    return __uint_as_float(((unsigned)h) << 16);
}

// ---------- fused setup: zero cnt (int4) + detect + weight prep ----------
__global__ __launch_bounds__(128) void setup_prep_kernel(int4* __restrict__ cntv,
                                                         const int* __restrict__ ei,
                                                         int* __restrict__ flag,
                                                         const float* __restrict__ W1,
                                                         const float* __restrict__ W2,
                                                         const float* __restrict__ W3,
                                                         const float* __restrict__ fcW,
                                                         ushort* __restrict__ i1,
                                                         ushort* __restrict__ i2,
                                                         ushort* __restrict__ i3,
                                                         ushort* __restrict__ ifc) {
    int b = blockIdx.x;
    int k = threadIdx.x;
    if (b < NZB) {
        int i = b * 128 + k;
        if (i < NN * CSTR / 4) cntv[i] = make_int4(0, 0, 0, 0);
    } else if (b == NZB) {
        __shared__ int nz;
        if (k == 0) nz = 0;
        __syncthreads();
        int c = 0;
        for (int i = k; i < 2048; i += 128)
            if (ei[2 * i + 1] != 0) c = 1;
        if (c) atomicAdd(&nz, 1);
        __syncthreads();
        if (k == 0) *flag = (nz == 0) ? 1 : 0;
    } else {
        int bb = b - (NZB + 1);        // 0..447
        if (bb < 384) {
            const float* W = (bb < 128) ? W1 : (bb < 256) ? W2 : W3;
            ushort* img = (bb < 128) ? i1 : (bb < 256) ? i2 : i3;
            int c = bb & 127;
            float w = W[(size_t)k * D + c];
            ushort hi = f2bf(w);
            ushort lo = f2bf(w - bf2f(hi));
            int ch = k >> 6, kk = k & 63, g = kk >> 3;
            int idx = c * 64 + ((g ^ (c & 7)) * 8) + (kk & 7);
            img[(size_t)(ch * 2 + 0) * 8192 + idx] = hi;
            img[(size_t)(ch * 2 + 1) * 8192 + idx] = lo;
        } else {
            int c = bb - 384;          // 0..63
            float w = (c < NC) ? fcW[(size_t)k * NC + c] : 0.0f;
            ushort hi = f2bf(w);
            ushort lo = f2bf(w - bf2f(hi));
            int g = k >> 3;
            int idx = c * 128 + ((g ^ (c & 7)) * 8) + (k & 7);
            ifc[idx] = hi;
            ifc[8192 + idx] = lo;
        }
    }
}

// ---------- fill: XCD-range partitioned bucket append, ILP x padded-cnt ----------
// Thread owns 8 contiguous edges; with 1 counter per 64B line the 8 atomics
// hit ~8 distinct lines -> RMW latencies overlap (R16's regression was
// line-contention, removed by CSTR padding). Sort canonicalizes order.
__global__ __launch_bounds__(256) void fill_kernel(const void* ei, const int* __restrict__ flag,
                                                   int* cnt, int* __restrict__ srcs) {
    int r = blockIdx.x & (NXCD - 1);
    int chunk = blockIdx.x >> 3;
    int base = chunk * EPB + threadIdx.x * 8;
    int dlo = r * DRANGE, dhi = dlo + DRANGE;
    int is64 = *flag;
    int s[8], d[8];
#pragma unroll
    for (int j = 0; j < 8; ++j) {
        int e = base + j;
        if (e < NE) load_edge(ei, e, is64, s[j], d[j]);
        else { s[j] = -1; d[j] = -1; }
    }
#pragma unroll
    for (int j = 0; j < 8; ++j) {
        int dd = d[j];
        if (dd < dlo || dd >= dhi || (unsigned)dd >= NN || (unsigned)s[j] >= NN) continue;
        int slot = atomicAdd(&cnt[dd * CSTR], 1);
        if (slot < CAP) srcs[dd * CAP + slot] = s[j];
    }
}

// ---------- dinv from final cnt ----------
__global__ __launch_bounds__(256) void dinv_kernel(const int* __restrict__ cnt,
                                                   float* __restrict__ dinv) {
    int i = blockIdx.x * 256 + threadIdx.x;
    if (i < NN) dinv[i] = 1.0f / sqrtf((float)cnt[i * CSTR] + 1.0f);   // +1 self-loop
}

// ---------- canonicalize buckets (bitonic sort) + precompute edge weights ----------
__global__ __launch_bounds__(256) void sort_kernel(const int* __restrict__ cnt,
                                                   int* __restrict__ srcs,
                                                   float* __restrict__ wts,
                                                   const float* __restrict__ dinv) {
    int wid = (blockIdx.x * 256 + threadIdx.x) >> 6;
    int lane = threadIdx.x & 63;
    if (wid >= NN) return;
    int deg = cnt[wid * CSTR]; if (deg > CAP) deg = CAP;
    if (deg == 0) return;
    float di = dinv[wid];
    int base = wid * CAP;
    int v = (lane < deg) ? srcs[base + lane] : 0x7fffffff;
#pragma unroll
    for (int k = 2; k <= 64; k <<= 1) {
#pragma unroll
        for (int j = k >> 1; j > 0; j >>= 1) {
            int o = __shfl_xor(v, j);
            bool up = ((lane & k) == 0);
            bool lower = ((lane & j) == 0);
            int mn = min(v, o), mx = max(v, o);
            v = (lower == up) ? mn : mx;
        }
    }
    if (lane < deg) {
        srcs[base + lane] = v;
        wts[base + lane] = dinv[v] * di;
    }
}

// ---------- GEMM from fp32 A (layer 1): T = A @ W, T fp16 ----------
__global__ __launch_bounds__(256, 2) void gemm_f32_kernel(const float* __restrict__ A,
                                                          const ushort* __restrict__ Wimg,
                                                          ushort* __restrict__ T) {
    __shared__ alignas(16) ushort sAh[8192];
    __shared__ alignas(16) ushort sAl[8192];
    __shared__ alignas(16) ushort sWh[8192];
    __shared__ alignas(16) ushort sWl[8192];
    int tid = threadIdx.x;
    int wave = tid >> 6, lane = tid & 63;
    int wr = wave >> 1, wc = wave & 1;
    int m0 = blockIdx.x * 128;
    f32x16 acc[2][2];
#pragma unroll
    for (int i = 0; i < 2; ++i)
#pragma unroll
        for (int j = 0; j < 2; ++j)
#pragma unroll
            for (int q = 0; q < 16; ++q) acc[i][j][q] = 0.0f;

    for (int ch = 0; ch < 2; ++ch) {
        const float4* wh = (const float4*)(Wimg + (size_t)(ch * 2 + 0) * 8192);
        const float4* wl = (const float4*)(Wimg + (size_t)(ch * 2 + 1) * 8192);
#pragma unroll
        for (int i = 0; i < 4; ++i) {
            ((float4*)sWh)[tid + i * 256] = wh[tid + i * 256];
            ((float4*)sWl)[tid + i * 256] = wl[tid + i * 256];
        }
#pragma unroll
        for (int p = 0; p < 8; ++p) {
            int idx = tid + p * 256;
            int r = idx >> 4;
            int kq = idx & 15;
            float4 v = make_float4(0, 0, 0, 0);
            int grow = m0 + r;
            if (grow < NN) v = *(const float4*)(A + (size_t)grow * D + ch * 64 + kq * 4);
            ushort4 h, l;
            h.x = f2bf(v.x); l.x = f2bf(v.x - bf2f(h.x));
            h.y = f2bf(v.y); l.y = f2bf(v.y - bf2f(h.y));
            h.z = f2bf(v.z); l.z = f2bf(v.z - bf2f(h.z));
            h.w = f2bf(v.w); l.w = f2bf(v.w - bf2f(h.w));
            int g = kq >> 1, half = kq & 1;
            int uidx = r * 64 + ((g ^ (r & 7)) * 8) + half * 4;
            *(ushort4*)&sAh[uidx] = h;
            *(ushort4*)&sAl[uidx] = l;
        }
        __syncthreads();

        int rb = wr * 64 + (lane & 31);
        int cb = wc * 64 + (lane & 31);
#pragma unroll
        for (int s = 0; s < 4; ++s) {
            int gg = s * 2 + (lane >> 5);
            int ra0 = rb, ra1 = rb + 32;
            int ca0 = cb, ca1 = cb + 32;
            bf16x8 ah0 = *(const bf16x8*)&sAh[ra0 * 64 + ((gg ^ (ra0 & 7)) * 8)];
            bf16x8 ah1 = *(const bf16x8*)&sAh[ra1 * 64 + ((gg ^ (ra1 & 7)) * 8)];
            bf16x8 al0 = *(const bf16x8*)&sAl[ra0 * 64 + ((gg ^ (ra0 & 7)) * 8)];
            bf16x8 al1 = *(const bf16x8*)&sAl[ra1 * 64 + ((gg ^ (ra1 & 7)) * 8)];
            bf16x8 wh0 = *(const bf16x8*)&sWh[ca0 * 64 + ((gg ^ (ca0 & 7)) * 8)];
            bf16x8 wh1 = *(const bf16x8*)&sWh[ca1 * 64 + ((gg ^ (ca1 & 7)) * 8)];
            bf16x8 wl0 = *(const bf16x8*)&sWl[ca0 * 64 + ((gg ^ (ca0 & 7)) * 8)];
            bf16x8 wl1 = *(const bf16x8*)&sWl[ca1 * 64 + ((gg ^ (ca1 & 7)) * 8)];
            acc[0][0] = __builtin_amdgcn_mfma_f32_32x32x16_bf16(ah0, wh0, acc[0][0], 0, 0, 0);
            acc[0][0] = __builtin_amdgcn_mfma_f32_32x32x16_bf16(ah0, wl0, acc[0][0], 0, 0, 0);
            acc[0][0] = __builtin_amdgcn_mfma_f32_32x32x16_bf16(al0, wh0, acc[0][0], 0, 0, 0);
            acc[0][1] = __builtin_amdgcn_mfma_f32_32x32x16_bf16(ah0, wh1, acc[0][1], 0, 0, 0);
            acc[0][1] = __builtin_amdgcn_mfma_f32_32x32x16_bf16(ah0, wl1, acc[0][1], 0, 0, 0);
            acc[0][1] = __builtin_amdgcn_mfma_f32_32x32x16_bf16(al0, wh1, acc[0][1], 0, 0, 0);
            acc[1][0] = __builtin_amdgcn_mfma_f32_32x32x16_bf16(ah1, wh0, acc[1][0], 0, 0, 0);
            acc[1][0] = __builtin_amdgcn_mfma_f32_32x32x16_bf16(ah1, wl0, acc[1][0], 0, 0, 0);
            acc[1][0] = __builtin_amdgcn_mfma_f32_32x32x16_bf16(al1, wh0, acc[1][0], 0, 0, 0);
            acc[1][1] = __builtin_amdgcn_mfma_f32_32x32x16_bf16(ah1, wh1, acc[1][1], 0, 0, 0);
            acc[1][1] = __builtin_amdgcn_mfma_f32_32x32x16_bf16(ah1, wl1, acc[1][1], 0, 0, 0);
            acc[1][1] = __builtin_amdgcn_mfma_f32_32x32x16_bf16(al1, wh1, acc[1][1], 0, 0, 0);
        }
        __syncthreads();
    }
#pragma unroll
    for (int rt = 0; rt < 2; ++rt)
#pragma unroll
        for (int ct = 0; ct < 2; ++ct) {
            int cg = wc * 64 + ct * 32 + (lane & 31);
#pragma unroll
            for (int reg = 0; reg < 16; ++reg) {
                int row = m0 + wr * 64 + rt * 32 + (reg & 3) + 8 * (reg >> 2) + 4 * (lane >> 5);
                if (row < NN)
                    T[(size_t)row * D + cg] = __half_as_ushort(__float2half(acc[rt][ct][reg]));
            }
        }
}

// ---------- GEMM from pre-split image A (layers 2,3): staging = linear copies ----------
__global__ __launch_bounds__(256, 2) void gemm_img_kernel(const ushort* __restrict__ Aimg,
                                                          const ushort* __restrict__ Wimg,
                                                          ushort* __restrict__ T) {
    __shared__ alignas(16) ushort sAh[8192];
    __shared__ alignas(16) ushort sAl[8192];
    __shared__ alignas(16) ushort sWh[8192];
    __shared__ alignas(16) ushort sWl[8192];
    int tid = threadIdx.x;
    int wave = tid >> 6, lane = tid & 63;
    int wr = wave >> 1, wc = wave & 1;
    int m0 = blockIdx.x * 128;
    const ushort* Atile = Aimg + (size_t)blockIdx.x * 32768;
    f32x16 acc[2][2];
#pragma unroll
    for (int i = 0; i < 2; ++i)
#pragma unroll
        for (int j = 0; j < 2; ++j)
#pragma unroll
            for (int q = 0; q < 16; ++q) acc[i][j][q] = 0.0f;

    for (int ch = 0; ch < 2; ++ch) {
        const float4* wh = (const float4*)(Wimg + (size_t)(ch * 2 + 0) * 8192);
        const float4* wl = (const float4*)(Wimg + (size_t)(ch * 2 + 1) * 8192);
        const float4* ah = (const float4*)(Atile + (size_t)(ch * 2 + 0) * 8192);
        const float4* al = (const float4*)(Atile + (size_t)(ch * 2 + 1) * 8192);
#pragma unroll
        for (int i = 0; i < 4; ++i) {
            ((float4*)sWh)[tid + i * 256] = wh[tid + i * 256];
            ((float4*)sWl)[tid + i * 256] = wl[tid + i * 256];
            ((float4*)sAh)[tid + i * 256] = ah[tid + i * 256];
            ((float4*)sAl)[tid + i * 256] = al[tid + i * 256];
        }
        __syncthreads();

        int rb = wr * 64 + (lane & 31);
        int cb = wc * 64 + (lane & 31);
#pragma unroll
        for (int s = 0; s < 4; ++s) {
            int gg = s * 2 + (lane >> 5);
            int ra0 = rb, ra1 = rb + 32;
            int ca0 = cb, ca1 = cb + 32;
            bf16x8 ah0 = *(const bf16x8*)&sAh[ra0 * 64 + ((gg ^ (ra0 & 7)) * 8)];
            bf16x8 ah1 = *(const bf16x8*)&sAh[ra1 * 64 + ((gg ^ (ra1 & 7)) * 8)];
            bf16x8 al0 = *(const bf16x8*)&sAl[ra0 * 64 + ((gg ^ (ra0 & 7)) * 8)];
            bf16x8 al1 = *(const bf16x8*)&sAl[ra1 * 64 + ((gg ^ (ra1 & 7)) * 8)];
            bf16x8 wh0 = *(const bf16x8*)&sWh[ca0 * 64 + ((gg ^ (ca0 & 7)) * 8)];
            bf16x8 wh1 = *(const bf16x8*)&sWh[ca1 * 64 + ((gg ^ (ca1 & 7)) * 8)];
            bf16x8 wl0 = *(const bf16x8*)&sWl[ca0 * 64 + ((gg ^ (ca0 & 7)) * 8)];
            bf16x8 wl1 = *(const bf16x8*)&sWl[ca1 * 64 + ((gg ^ (ca1 & 7)) * 8)];
            acc[0][0] = __builtin_amdgcn_mfma_f32_32x32x16_bf16(ah0, wh0, acc[0][0], 0, 0, 0);
            acc[0][0] = __builtin_amdgcn_mfma_f32_32x32x16_bf16(ah0, wl0, acc[0][0], 0, 0, 0);
            acc[0][0] = __builtin_amdgcn_mfma_f32_32x32x16_bf16(al0, wh0, acc[0][0], 0, 0, 0);
            acc[0][1] = __builtin_amdgcn_mfma_f32_32x32x16_bf16(ah0, wh1, acc[0][1], 0, 0, 0);
            acc[0][1] = __builtin_amdgcn_mfma_f32_32x32x16_bf16(ah0, wl1, acc[0][1], 0, 0, 0);
            acc[0][1] = __builtin_amdgcn_mfma_f32_32x32x16_bf16(al0, wh1, acc[0][1], 0, 0, 0);
            acc[1][0] = __builtin_amdgcn_mfma_f32_32x32x16_bf16(ah1, wh0, acc[1][0], 0, 0, 0);
            acc[1][0] = __builtin_amdgcn_mfma_f32_32x32x16_bf16(ah1, wl0, acc[1][0], 0, 0, 0);
            acc[1][0] = __builtin_amdgcn_mfma_f32_32x32x16_bf16(al1, wh0, acc[1][0], 0, 0, 0);
            acc[1][1] = __builtin_amdgcn_mfma_f32_32x32x16_bf16(ah1, wh1, acc[1][1], 0, 0, 0);
            acc[1][1] = __builtin_amdgcn_mfma_f32_32x32x16_bf16(ah1, wl1, acc[1][1], 0, 0, 0);
            acc[1][1] = __builtin_amdgcn_mfma_f32_32x32x16_bf16(al1, wh1, acc[1][1], 0, 0, 0);
        }
        __syncthreads();
    }
#pragma unroll
    for (int rt = 0; rt < 2; ++rt)
#pragma unroll
        for (int ct = 0; ct < 2; ++ct) {
            int cg = wc * 64 + ct * 32 + (lane & 31);
#pragma unroll
            for (int reg = 0; reg < 16; ++reg) {
                int row = m0 + wr * 64 + rt * 32 + (reg & 3) + 8 * (reg >> 2) + 4 * (lane >> 5);
                if (row < NN)
                    T[(size_t)row * D + cg] = __half_as_ushort(__float2half(acc[rt][ct][reg]));
            }
        }
}

// ---------- FC via split-bf16 MFMA ----------
__global__ __launch_bounds__(256, 2) void fc_mfma_kernel(const float* __restrict__ A,
                                                         const ushort* __restrict__ img,
                                                         const float* __restrict__ b,
                                                         float* __restrict__ O) {
    __shared__ alignas(16) ushort sAh[8192];
    __shared__ alignas(16) ushort sAl[8192];
    __shared__ alignas(16) ushort sWh[8192];
    __shared__ alignas(16) ushort sWl[8192];
    int tid = threadIdx.x;
    int wave = tid >> 6, lane = tid & 63;
    int m0 = blockIdx.x * 128;
#pragma unroll
    for (int i = 0; i < 4; ++i) {
        ((float4*)sWh)[tid + i * 256] = ((const float4*)img)[tid + i * 256];
        ((float4*)sWl)[tid + i * 256] = ((const float4*)(img + 8192))[tid + i * 256];
    }
    f32x16 acc[2];
#pragma unroll
    for (int j = 0; j < 2; ++j)
#pragma unroll
        for (int q = 0; q < 16; ++q) acc[j][q] = 0.0f;

    for (int ch = 0; ch < 2; ++ch) {
#pragma unroll
        for (int p = 0; p < 8; ++p) {
            int idx = tid + p * 256;
            int r = idx >> 4;
            int kq = idx & 15;
            float4 v = make_float4(0, 0, 0, 0);
            int grow = m0 + r;
            if (grow < NN) v = *(const float4*)(A + (size_t)grow * D + ch * 64 + kq * 4);
            ushort4 h, l;
            h.x = f2bf(v.x); l.x = f2bf(v.x - bf2f(h.x));
            h.y = f2bf(v.y); l.y = f2bf(v.y - bf2f(h.y));
            h.z = f2bf(v.z); l.z = f2bf(v.z - bf2f(h.z));
            h.w = f2bf(v.w); l.w = f2bf(v.w - bf2f(h.w));
            int g = kq >> 1, half = kq & 1;
            int uidx = r * 64 + ((g ^ (r & 7)) * 8) + half * 4;
            *(ushort4*)&sAh[uidx] = h;
            *(ushort4*)&sAl[uidx] = l;
        }
        __syncthreads();
        int ra = wave * 32 + (lane & 31);
        int c0 = lane & 31, c1 = 32 + (lane & 31);
#pragma unroll
        for (int s = 0; s < 4; ++s) {
            int gg = s * 2 + (lane >> 5);
            int kg = ch * 8 + gg;
            bf16x8 ah = *(const bf16x8*)&sAh[ra * 64 + ((gg ^ (ra & 7)) * 8)];
            bf16x8 al = *(const bf16x8*)&sAl[ra * 64 + ((gg ^ (ra & 7)) * 8)];
            bf16x8 wh0 = *(const bf16x8*)&sWh[c0 * 128 + ((kg ^ (c0 & 7)) * 8)];
            bf16x8 wl0 = *(const bf16x8*)&sWl[c0 * 128 + ((kg ^ (c0 & 7)) * 8)];
            bf16x8 wh1 = *(const bf16x8*)&sWh[c1 * 128 + ((kg ^ (c1 & 7)) * 8)];
            bf16x8 wl1 = *(const bf16x8*)&sWl[c1 * 128 + ((kg ^ (c1 & 7)) * 8)];
            acc[0] = __builtin_amdgcn_mfma_f32_32x32x16_bf16(ah, wh0, acc[0], 0, 0, 0);
            acc[0] = __builtin_amdgcn_mfma_f32_32x32x16_bf16(ah, wl0, acc[0], 0, 0, 0);
            acc[0] = __builtin_amdgcn_mfma_f32_32x32x16_bf16(al, wh0, acc[0], 0, 0, 0);
            acc[1] = __builtin_amdgcn_mfma_f32_32x32x16_bf16(ah, wh1, acc[1], 0, 0, 0);
            acc[1] = __builtin_amdgcn_mfma_f32_32x32x16_bf16(ah, wl1, acc[1], 0, 0, 0);
            acc[1] = __builtin_amdgcn_mfma_f32_32x32x16_bf16(al, wh1, acc[1], 0, 0, 0);
        }
        __syncthreads();
    }
#pragma unroll
    for (int ct = 0; ct < 2; ++ct) {
        int col = ct * 32 + (lane & 31);
        if (col < NC) {
            float bb = b[col];
#pragma unroll
            for (int reg = 0; reg < 16; ++reg) {
                int row = m0 + wave * 32 + (reg & 3) + 8 * (reg >> 2) + 4 * (lane >> 5);
                if (row < NN) O[(size_t)row * NC + col] = acc[ct][reg] + bb;
            }
        }
    }
}

// ---------- fp16 helpers ----------
__device__ __forceinline__ float4 h4load(const ushort* __restrict__ T, int row, int l) {
    uint2 hv = ((const uint2*)(T + (size_t)row * D))[l];
    __half2 h0 = *(__half2*)&hv.x, h1 = *(__half2*)&hv.y;
    float2 f0 = __half22float2(h0), f1 = __half22float2(h1);
    return make_float4(f0.x, f0.y, f1.x, f1.y);
}

__device__ __forceinline__ void fma4(float4& a, float4 v, float w) {
    a.x = fmaf(v.x, w, a.x); a.y = fmaf(v.y, w, a.y);
    a.z = fmaf(v.z, w, a.z); a.w = fmaf(v.w, w, a.w);
}

// ---------- bucket pull, HALF-WAVE per dst; lane-resident srcs/wts + shfl ----------
template<int IMG>
__global__ __launch_bounds__(256) void aggregate_kernel(const ushort* __restrict__ T,
                                                        const int* __restrict__ cnt,
                                                        const int* __restrict__ srcs,
                                                        const float* __restrict__ wts,
                                                        const float* __restrict__ dinv,
                                                        const float* __restrict__ b,
                                                        float* __restrict__ out,
                                                        ushort* __restrict__ img) {
    int wid = (blockIdx.x * 256 + threadIdx.x) >> 5;   // half-wave id = dst node
    int l = threadIdx.x & 31;
    if (wid >= NN) return;
    float di = dinv[wid];
    float wself = di * di;
    float4 acc = h4load(T, wid, l);
    acc.x *= wself; acc.y *= wself; acc.z *= wself; acc.w *= wself;
    int base = wid * CAP;
    int deg = cnt[wid * CSTR]; if (deg > CAP) deg = CAP;
    int lim = deg < 32 ? deg : 32;
    int sreg = 0; float wreg = 0.0f;
    if (l < lim) { sreg = srcs[base + l]; wreg = wts[base + l]; }
    int e = 0;
    for (; e + 7 < lim; e += 8) {
        int s0 = __shfl(sreg, e + 0, 32), s1 = __shfl(sreg, e + 1, 32);
        int s2 = __shfl(sreg, e + 2, 32), s3 = __shfl(sreg, e + 3, 32);
        int s4 = __shfl(sreg, e + 4, 32), s5 = __shfl(sreg, e + 5, 32);
        int s6 = __shfl(sreg, e + 6, 32), s7 = __shfl(sreg, e + 7, 32);
        float4 v0 = h4load(T, s0, l), v1 = h4load(T, s1, l);
        float4 v2 = h4load(T, s2, l), v3 = h4load(T, s3, l);
        float4 v4 = h4load(T, s4, l), v5 = h4load(T, s5, l);
        float4 v6 = h4load(T, s6, l), v7 = h4load(T, s7, l);
        fma4(acc, v0, __shfl(wreg, e + 0, 32)); fma4(acc, v1, __shfl(wreg, e + 1, 32));
        fma4(acc, v2, __shfl(wreg, e + 2, 32)); fma4(acc, v3, __shfl(wreg, e + 3, 32));
        fma4(acc, v4, __shfl(wreg, e + 4, 32)); fma4(acc, v5, __shfl(wreg, e + 5, 32));
        fma4(acc, v6, __shfl(wreg, e + 6, 32)); fma4(acc, v7, __shfl(wreg, e + 7, 32));
    }
    for (; e + 3 < lim; e += 4) {
        int s0 = __shfl(sreg, e + 0, 32), s1 = __shfl(sreg, e + 1, 32);
        int s2 = __shfl(sreg, e + 2, 32), s3 = __shfl(sreg, e + 3, 32);
        float4 v0 = h4load(T, s0, l), v1 = h4load(T, s1, l);
        float4 v2 = h4load(T, s2, l), v3 = h4load(T, s3, l);
        fma4(acc, v0, __shfl(wreg, e + 0, 32)); fma4(acc, v1, __shfl(wreg, e + 1, 32));
        fma4(acc, v2, __shfl(wreg, e + 2, 32)); fma4(acc, v3, __shfl(wreg, e + 3, 32));
    }
    for (; e < lim; ++e) {
        fma4(acc, h4load(T, __shfl(sreg, e, 32), l), __shfl(wreg, e, 32));
    }
    for (; e < deg; ++e) {        // rare deg>32 tail
        fma4(acc, h4load(T, srcs[base + e], l), wts[base + e]);
    }
    float4 bb = ((const float4*)b)[l];
    acc.x = fmaxf(acc.x + bb.x, 0.0f);
    acc.y = fmaxf(acc.y + bb.y, 0.0f);
    acc.z = fmaxf(acc.z + bb.z, 0.0f);
    acc.w = fmaxf(acc.w + bb.w, 0.0f);
    if (IMG) {
        int tile = wid >> 7, rr = wid & 127;
        int c0 = 4 * l;
        int ch = c0 >> 6, kk = c0 & 63, g = kk >> 3;
        int idx = rr * 64 + ((g ^ (rr & 7)) * 8) + (kk & 7);
        ushort4 hh, ll;
        hh.x = f2bf(acc.x); ll.x = f2bf(acc.x - bf2f(hh.x));
        hh.y = f2bf(acc.y); ll.y = f2bf(acc.y - bf2f(hh.y));
        hh.z = f2bf(acc.z); ll.z = f2bf(acc.z - bf2f(hh.z));
        hh.w = f2bf(acc.w); ll.w = f2bf(acc.w - bf2f(hh.w));
        ushort* bimg = img + (size_t)tile * 32768;
        *(ushort4*)(bimg + (size_t)(ch * 2 + 0) * 8192 + idx) = hh;
        *(ushort4*)(bimg + (size_t)(ch * 2 + 1) * 8192 + idx) = ll;
    } else {
        ((float4*)(out + (size_t)wid * D))[l] = acc;
    }
}

extern "C" void kernel_launch(void* const* d_in, const int* in_sizes, int n_in,
                              void* d_out, int out_size, void* d_ws, size_t ws_size,
                              hipStream_t stream) {
    const float* x   = (const float*)d_in[0];
    const void*  ei  = d_in[1];
    const float* W1  = (const float*)d_in[2];
    const float* b1  = (const float*)d_in[3];
    const float* W2  = (const float*)d_in[4];
    const float* b2  = (const float*)d_in[5];
    const float* W3  = (const float*)d_in[6];
    const float* b3  = (const float*)d_in[7];
    const float* fcW = (const float*)d_in[8];
    const float* fcb = (const float*)d_in[9];

    float* out_h  = (float*)d_out;                       // [NN x 128]
    float* out_fc = out_h + (size_t)NN * D;              // [NN x 40]

    size_t off = 0;
    auto alloc = [&](size_t bytes) {
        void* p = (char*)d_ws + off;
        off += (bytes + 255) & ~(size_t)255;
        return p;
    };
    float*  dinv   = (float*) alloc((size_t)NN * 4);
    int*    cnt    = (int*)   alloc((size_t)NN * CSTR * 4);      // 3.2 MB (line-padded)
    int*    flag   = (int*)   alloc(256);
    int*    srcs   = (int*)   alloc((size_t)NN * CAP * 4);       // 12.8 MB
    float*  wts    = (float*) alloc((size_t)NN * CAP * 4);       // 12.8 MB
    ushort* bufT   = (ushort*)alloc((size_t)NN * D * 2);         // 12.8 MB
    ushort* himg   = (ushort*)alloc((size_t)NTILE * 32768 * 2);  // 25.6 MB
    ushort* wimg1  = (ushort*)alloc(32768 * 2);
    ushort* wimg2  = (ushort*)alloc(32768 * 2);
    ushort* wimg3  = (ushort*)alloc(32768 * 2);
    ushort* fcimg  = (ushort*)alloc(16384 * 2);
    (void)ws_size; (void)in_sizes; (void)n_in; (void)out_size;

    setup_prep_kernel<<<NZB + 1 + 448, 128, 0, stream>>>((int4*)cnt, (const int*)ei, flag,
                                                         W1, W2, W3, fcW,
                                                         wimg1, wimg2, wimg3, fcimg);
    fill_kernel<<<NCH * NXCD, 256, 0, stream>>>(ei, flag, cnt, srcs);
    dinv_kernel<<<NBLK, 256, 0, stream>>>(cnt, dinv);
    sort_kernel<<<(NN * 64 + 255) / 256, 256, 0, stream>>>(cnt, srcs, wts, dinv);

    int agg_grid = (NN * 32 + 255) / 256;   // half-wave per dst
    // layer 1: x (fp32) -> T -> h image
    gemm_f32_kernel<<<NTILE, 256, 0, stream>>>(x, wimg1, bufT);
    aggregate_kernel<1><<<agg_grid, 256, 0, stream>>>(bufT, cnt, srcs, wts, dinv, b1, nullptr, himg);
    // layer 2: h image -> T -> h image
    gemm_img_kernel<<<NTILE, 256, 0, stream>>>(himg, wimg2, bufT);
    aggregate_kernel<1><<<agg_grid, 256, 0, stream>>>(bufT, cnt, srcs, wts, dinv, b2, nullptr, himg);
    // layer 3: h image -> T -> fp32 h (d_out)
    gemm_img_kernel<<<NTILE, 256, 0, stream>>>(himg, wimg3, bufT);
    aggregate_kernel<0><<<agg_grid, 256, 0, stream>>>(bufT, cnt, srcs, wts, dinv, b3, out_h, nullptr);

    fc_mfma_kernel<<<NTILE, 256, 0, stream>>>(out_h, fcimg, fcb, out_fc);
}

// Round 19
// 208.479 us; speedup vs baseline: 1.0327x; 1.0327x over previous
//
#include <hip/hip_runtime.h>
#include <hip/hip_fp16.h>

#define NN 50000
#define NE 800000
#define D  128
#define NC 40
#define NBLK ((NN + 255) / 256)
#define NXCD 8
#define DRANGE ((NN + NXCD - 1) / NXCD)   // 6250
#define EPB 2048
#define NCH ((NE + EPB - 1) / EPB)        // 391
#define CAP 64                             // bucket capacity (Poisson(16): P(>64)~1e-19)
#define NTILE ((NN + 127) / 128)           // 391 gemm tiles
#define CSTR 16                            // cnt stride (ints): 1 counter per 64B line
#define NZB ((NN * CSTR / 4 + 127) / 128)  // int4-zero blocks for cnt

typedef short bf16x8 __attribute__((ext_vector_type(8)));
typedef float f32x16 __attribute__((ext_vector_type(16)));

// ---------- edge loading (int32/int64 auto-detect) ----------
__device__ __forceinline__ void load_edge(const void* ei, int e, int is64, int& s, int& d) {
    if (is64) {
        const long long* p = (const long long*)ei;
        s = (int)p[e]; d = (int)p[NE + e];
    } else {
        const int* p = (const int*)ei;
        s = p[e]; d = p[NE + e];
    }
}

// ---------- bf16 split helpers ----------
__device__ __forceinline__ ushort f2bf(float x) {
    unsigned u = __float_as_uint(x);
    return (ushort)((u + 0x7fffu + ((u >> 16) & 1u)) >> 16);
}
__device__ __forceinline__ float bf2f(ushort h) {
    return __uint_as_float(((unsigned)h) << 16);
}

// ---------- fused setup: zero cnt (int4) + detect + weight prep ----------
__global__ __launch_bounds__(128) void setup_prep_kernel(int4* __restrict__ cntv,
                                                         const int* __restrict__ ei,
                                                         int* __restrict__ flag,
                                                         const float* __restrict__ W1,
                                                         const float* __restrict__ W2,
                                                         const float* __restrict__ W3,
                                                         const float* __restrict__ fcW,
                                                         ushort* __restrict__ i1,
                                                         ushort* __restrict__ i2,
                                                         ushort* __restrict__ i3,
                                                         ushort* __restrict__ ifc) {
    int b = blockIdx.x;
    int k = threadIdx.x;
    if (b < NZB) {
        int i = b * 128 + k;
        if (i < NN * CSTR / 4) cntv[i] = make_int4(0, 0, 0, 0);
    } else if (b == NZB) {
        __shared__ int nz;
        if (k == 0) nz = 0;
        __syncthreads();
        int c = 0;
        for (int i = k; i < 2048; i += 128)
            if (ei[2 * i + 1] != 0) c = 1;
        if (c) atomicAdd(&nz, 1);
        __syncthreads();
        if (k == 0) *flag = (nz == 0) ? 1 : 0;
    } else {
        int bb = b - (NZB + 1);        // 0..447
        if (bb < 384) {
            const float* W = (bb < 128) ? W1 : (bb < 256) ? W2 : W3;
            ushort* img = (bb < 128) ? i1 : (bb < 256) ? i2 : i3;
            int c = bb & 127;
            float w = W[(size_t)k * D + c];
            ushort hi = f2bf(w);
            ushort lo = f2bf(w - bf2f(hi));
            int ch = k >> 6, kk = k & 63, g = kk >> 3;
            int idx = c * 64 + ((g ^ (c & 7)) * 8) + (kk & 7);
            img[(size_t)(ch * 2 + 0) * 8192 + idx] = hi;
            img[(size_t)(ch * 2 + 1) * 8192 + idx] = lo;
        } else {
            int c = bb - 384;          // 0..63
            float w = (c < NC) ? fcW[(size_t)k * NC + c] : 0.0f;
            ushort hi = f2bf(w);
            ushort lo = f2bf(w - bf2f(hi));
            int g = k >> 3;
            int idx = c * 128 + ((g ^ (c & 7)) * 8) + (k & 7);
            ifc[idx] = hi;
            ifc[8192 + idx] = lo;
        }
    }
}

// ---------- fill: XCD-range partitioned bucket append (strided; TLP >> ILP) ----------
// One edge per thread per iteration (stride 256): maximal independent atomic
// streams. ILP-batched variants regressed in BOTH cnt layouts (R16/R18).
// cnt padded 1 counter/64B line kills same-line RMW serialization (R17 win).
__global__ __launch_bounds__(256) void fill_kernel(const void* ei, const int* __restrict__ flag,
                                                   int* cnt, int* __restrict__ srcs) {
    int r = blockIdx.x & (NXCD - 1);
    int chunk = blockIdx.x >> 3;
    int base = chunk * EPB;
    int dlo = r * DRANGE, dhi = dlo + DRANGE;
    int is64 = *flag;
#pragma unroll
    for (int j = 0; j < EPB / 256; ++j) {
        int e = base + threadIdx.x + j * 256;
        if (e >= NE) break;
        int s, d; load_edge(ei, e, is64, s, d);
        if (d < dlo || d >= dhi || (unsigned)d >= NN || (unsigned)s >= NN) continue;
        int slot = atomicAdd(&cnt[d * CSTR], 1);
        if (slot < CAP) srcs[d * CAP + slot] = s;
    }
}

// ---------- dinv from final cnt ----------
__global__ __launch_bounds__(256) void dinv_kernel(const int* __restrict__ cnt,
                                                   float* __restrict__ dinv) {
    int i = blockIdx.x * 256 + threadIdx.x;
    if (i < NN) dinv[i] = 1.0f / sqrtf((float)cnt[i * CSTR] + 1.0f);   // +1 self-loop
}

// ---------- canonicalize buckets (bitonic sort) + precompute edge weights ----------
__global__ __launch_bounds__(256) void sort_kernel(const int* __restrict__ cnt,
                                                   int* __restrict__ srcs,
                                                   float* __restrict__ wts,
                                                   const float* __restrict__ dinv) {
    int wid = (blockIdx.x * 256 + threadIdx.x) >> 6;
    int lane = threadIdx.x & 63;
    if (wid >= NN) return;
    int deg = cnt[wid * CSTR]; if (deg > CAP) deg = CAP;
    if (deg == 0) return;
    float di = dinv[wid];
    int base = wid * CAP;
    int v = (lane < deg) ? srcs[base + lane] : 0x7fffffff;
#pragma unroll
    for (int k = 2; k <= 64; k <<= 1) {
#pragma unroll
        for (int j = k >> 1; j > 0; j >>= 1) {
            int o = __shfl_xor(v, j);
            bool up = ((lane & k) == 0);
            bool lower = ((lane & j) == 0);
            int mn = min(v, o), mx = max(v, o);
            v = (lower == up) ? mn : mx;
        }
    }
    if (lane < deg) {
        srcs[base + lane] = v;
        wts[base + lane] = dinv[v] * di;
    }
}

// ---------- GEMM from fp32 A (layer 1): T = A @ W, T fp16 ----------
__global__ __launch_bounds__(256, 2) void gemm_f32_kernel(const float* __restrict__ A,
                                                          const ushort* __restrict__ Wimg,
                                                          ushort* __restrict__ T) {
    __shared__ alignas(16) ushort sAh[8192];
    __shared__ alignas(16) ushort sAl[8192];
    __shared__ alignas(16) ushort sWh[8192];
    __shared__ alignas(16) ushort sWl[8192];
    int tid = threadIdx.x;
    int wave = tid >> 6, lane = tid & 63;
    int wr = wave >> 1, wc = wave & 1;
    int m0 = blockIdx.x * 128;
    f32x16 acc[2][2];
#pragma unroll
    for (int i = 0; i < 2; ++i)
#pragma unroll
        for (int j = 0; j < 2; ++j)
#pragma unroll
            for (int q = 0; q < 16; ++q) acc[i][j][q] = 0.0f;

    for (int ch = 0; ch < 2; ++ch) {
        const float4* wh = (const float4*)(Wimg + (size_t)(ch * 2 + 0) * 8192);
        const float4* wl = (const float4*)(Wimg + (size_t)(ch * 2 + 1) * 8192);
#pragma unroll
        for (int i = 0; i < 4; ++i) {
            ((float4*)sWh)[tid + i * 256] = wh[tid + i * 256];
            ((float4*)sWl)[tid + i * 256] = wl[tid + i * 256];
        }
#pragma unroll
        for (int p = 0; p < 8; ++p) {
            int idx = tid + p * 256;
            int r = idx >> 4;
            int kq = idx & 15;
            float4 v = make_float4(0, 0, 0, 0);
            int grow = m0 + r;
            if (grow < NN) v = *(const float4*)(A + (size_t)grow * D + ch * 64 + kq * 4);
            ushort4 h, l;
            h.x = f2bf(v.x); l.x = f2bf(v.x - bf2f(h.x));
            h.y = f2bf(v.y); l.y = f2bf(v.y - bf2f(h.y));
            h.z = f2bf(v.z); l.z = f2bf(v.z - bf2f(h.z));
            h.w = f2bf(v.w); l.w = f2bf(v.w - bf2f(h.w));
            int g = kq >> 1, half = kq & 1;
            int uidx = r * 64 + ((g ^ (r & 7)) * 8) + half * 4;
            *(ushort4*)&sAh[uidx] = h;
            *(ushort4*)&sAl[uidx] = l;
        }
        __syncthreads();

        int rb = wr * 64 + (lane & 31);
        int cb = wc * 64 + (lane & 31);
#pragma unroll
        for (int s = 0; s < 4; ++s) {
            int gg = s * 2 + (lane >> 5);
            int ra0 = rb, ra1 = rb + 32;
            int ca0 = cb, ca1 = cb + 32;
            bf16x8 ah0 = *(const bf16x8*)&sAh[ra0 * 64 + ((gg ^ (ra0 & 7)) * 8)];
            bf16x8 ah1 = *(const bf16x8*)&sAh[ra1 * 64 + ((gg ^ (ra1 & 7)) * 8)];
            bf16x8 al0 = *(const bf16x8*)&sAl[ra0 * 64 + ((gg ^ (ra0 & 7)) * 8)];
            bf16x8 al1 = *(const bf16x8*)&sAl[ra1 * 64 + ((gg ^ (ra1 & 7)) * 8)];
            bf16x8 wh0 = *(const bf16x8*)&sWh[ca0 * 64 + ((gg ^ (ca0 & 7)) * 8)];
            bf16x8 wh1 = *(const bf16x8*)&sWh[ca1 * 64 + ((gg ^ (ca1 & 7)) * 8)];
            bf16x8 wl0 = *(const bf16x8*)&sWl[ca0 * 64 + ((gg ^ (ca0 & 7)) * 8)];
            bf16x8 wl1 = *(const bf16x8*)&sWl[ca1 * 64 + ((gg ^ (ca1 & 7)) * 8)];
            acc[0][0] = __builtin_amdgcn_mfma_f32_32x32x16_bf16(ah0, wh0, acc[0][0], 0, 0, 0);
            acc[0][0] = __builtin_amdgcn_mfma_f32_32x32x16_bf16(ah0, wl0, acc[0][0], 0, 0, 0);
            acc[0][0] = __builtin_amdgcn_mfma_f32_32x32x16_bf16(al0, wh0, acc[0][0], 0, 0, 0);
            acc[0][1] = __builtin_amdgcn_mfma_f32_32x32x16_bf16(ah0, wh1, acc[0][1], 0, 0, 0);
            acc[0][1] = __builtin_amdgcn_mfma_f32_32x32x16_bf16(ah0, wl1, acc[0][1], 0, 0, 0);
            acc[0][1] = __builtin_amdgcn_mfma_f32_32x32x16_bf16(al0, wh1, acc[0][1], 0, 0, 0);
            acc[1][0] = __builtin_amdgcn_mfma_f32_32x32x16_bf16(ah1, wh0, acc[1][0], 0, 0, 0);
            acc[1][0] = __builtin_amdgcn_mfma_f32_32x32x16_bf16(ah1, wl0, acc[1][0], 0, 0, 0);
            acc[1][0] = __builtin_amdgcn_mfma_f32_32x32x16_bf16(al1, wh0, acc[1][0], 0, 0, 0);
            acc[1][1] = __builtin_amdgcn_mfma_f32_32x32x16_bf16(ah1, wh1, acc[1][1], 0, 0, 0);
            acc[1][1] = __builtin_amdgcn_mfma_f32_32x32x16_bf16(ah1, wl1, acc[1][1], 0, 0, 0);
            acc[1][1] = __builtin_amdgcn_mfma_f32_32x32x16_bf16(al1, wh1, acc[1][1], 0, 0, 0);
        }
        __syncthreads();
    }
#pragma unroll
    for (int rt = 0; rt < 2; ++rt)
#pragma unroll
        for (int ct = 0; ct < 2; ++ct) {
            int cg = wc * 64 + ct * 32 + (lane & 31);
#pragma unroll
            for (int reg = 0; reg < 16; ++reg) {
                int row = m0 + wr * 64 + rt * 32 + (reg & 3) + 8 * (reg >> 2) + 4 * (lane >> 5);
                if (row < NN)
                    T[(size_t)row * D + cg] = __half_as_ushort(__float2half(acc[rt][ct][reg]));
            }
        }
}

// ---------- GEMM from pre-split image A (layers 2,3): staging = linear copies ----------
__global__ __launch_bounds__(256, 2) void gemm_img_kernel(const ushort* __restrict__ Aimg,
                                                          const ushort* __restrict__ Wimg,
                                                          ushort* __restrict__ T) {
    __shared__ alignas(16) ushort sAh[8192];
    __shared__ alignas(16) ushort sAl[8192];
    __shared__ alignas(16) ushort sWh[8192];
    __shared__ alignas(16) ushort sWl[8192];
    int tid = threadIdx.x;
    int wave = tid >> 6, lane = tid & 63;
    int wr = wave >> 1, wc = wave & 1;
    int m0 = blockIdx.x * 128;
    const ushort* Atile = Aimg + (size_t)blockIdx.x * 32768;
    f32x16 acc[2][2];
#pragma unroll
    for (int i = 0; i < 2; ++i)
#pragma unroll
        for (int j = 0; j < 2; ++j)
#pragma unroll
            for (int q = 0; q < 16; ++q) acc[i][j][q] = 0.0f;

    for (int ch = 0; ch < 2; ++ch) {
        const float4* wh = (const float4*)(Wimg + (size_t)(ch * 2 + 0) * 8192);
        const float4* wl = (const float4*)(Wimg + (size_t)(ch * 2 + 1) * 8192);
        const float4* ah = (const float4*)(Atile + (size_t)(ch * 2 + 0) * 8192);
        const float4* al = (const float4*)(Atile + (size_t)(ch * 2 + 1) * 8192);
#pragma unroll
        for (int i = 0; i < 4; ++i) {
            ((float4*)sWh)[tid + i * 256] = wh[tid + i * 256];
            ((float4*)sWl)[tid + i * 256] = wl[tid + i * 256];
            ((float4*)sAh)[tid + i * 256] = ah[tid + i * 256];
            ((float4*)sAl)[tid + i * 256] = al[tid + i * 256];
        }
        __syncthreads();

        int rb = wr * 64 + (lane & 31);
        int cb = wc * 64 + (lane & 31);
#pragma unroll
        for (int s = 0; s < 4; ++s) {
            int gg = s * 2 + (lane >> 5);
            int ra0 = rb, ra1 = rb + 32;
            int ca0 = cb, ca1 = cb + 32;
            bf16x8 ah0 = *(const bf16x8*)&sAh[ra0 * 64 + ((gg ^ (ra0 & 7)) * 8)];
            bf16x8 ah1 = *(const bf16x8*)&sAh[ra1 * 64 + ((gg ^ (ra1 & 7)) * 8)];
            bf16x8 al0 = *(const bf16x8*)&sAl[ra0 * 64 + ((gg ^ (ra0 & 7)) * 8)];
            bf16x8 al1 = *(const bf16x8*)&sAl[ra1 * 64 + ((gg ^ (ra1 & 7)) * 8)];
            bf16x8 wh0 = *(const bf16x8*)&sWh[ca0 * 64 + ((gg ^ (ca0 & 7)) * 8)];
            bf16x8 wh1 = *(const bf16x8*)&sWh[ca1 * 64 + ((gg ^ (ca1 & 7)) * 8)];
            bf16x8 wl0 = *(const bf16x8*)&sWl[ca0 * 64 + ((gg ^ (ca0 & 7)) * 8)];
            bf16x8 wl1 = *(const bf16x8*)&sWl[ca1 * 64 + ((gg ^ (ca1 & 7)) * 8)];
            acc[0][0] = __builtin_amdgcn_mfma_f32_32x32x16_bf16(ah0, wh0, acc[0][0], 0, 0, 0);
            acc[0][0] = __builtin_amdgcn_mfma_f32_32x32x16_bf16(ah0, wl0, acc[0][0], 0, 0, 0);
            acc[0][0] = __builtin_amdgcn_mfma_f32_32x32x16_bf16(al0, wh0, acc[0][0], 0, 0, 0);
            acc[0][1] = __builtin_amdgcn_mfma_f32_32x32x16_bf16(ah0, wh1, acc[0][1], 0, 0, 0);
            acc[0][1] = __builtin_amdgcn_mfma_f32_32x32x16_bf16(ah0, wl1, acc[0][1], 0, 0, 0);
            acc[0][1] = __builtin_amdgcn_mfma_f32_32x32x16_bf16(al0, wh1, acc[0][1], 0, 0, 0);
            acc[1][0] = __builtin_amdgcn_mfma_f32_32x32x16_bf16(ah1, wh0, acc[1][0], 0, 0, 0);
            acc[1][0] = __builtin_amdgcn_mfma_f32_32x32x16_bf16(ah1, wl0, acc[1][0], 0, 0, 0);
            acc[1][0] = __builtin_amdgcn_mfma_f32_32x32x16_bf16(al1, wh0, acc[1][0], 0, 0, 0);
            acc[1][1] = __builtin_amdgcn_mfma_f32_32x32x16_bf16(ah1, wh1, acc[1][1], 0, 0, 0);
            acc[1][1] = __builtin_amdgcn_mfma_f32_32x32x16_bf16(ah1, wl1, acc[1][1], 0, 0, 0);
            acc[1][1] = __builtin_amdgcn_mfma_f32_32x32x16_bf16(al1, wh1, acc[1][1], 0, 0, 0);
        }
        __syncthreads();
    }
#pragma unroll
    for (int rt = 0; rt < 2; ++rt)
#pragma unroll
        for (int ct = 0; ct < 2; ++ct) {
            int cg = wc * 64 + ct * 32 + (lane & 31);
#pragma unroll
            for (int reg = 0; reg < 16; ++reg) {
                int row = m0 + wr * 64 + rt * 32 + (reg & 3) + 8 * (reg >> 2) + 4 * (lane >> 5);
                if (row < NN)
                    T[(size_t)row * D + cg] = __half_as_ushort(__float2half(acc[rt][ct][reg]));
            }
        }
}

// ---------- FC via split-bf16 MFMA ----------
__global__ __launch_bounds__(256, 2) void fc_mfma_kernel(const float* __restrict__ A,
                                                         const ushort* __restrict__ img,
                                                         const float* __restrict__ b,
                                                         float* __restrict__ O) {
    __shared__ alignas(16) ushort sAh[8192];
    __shared__ alignas(16) ushort sAl[8192];
    __shared__ alignas(16) ushort sWh[8192];
    __shared__ alignas(16) ushort sWl[8192];
    int tid = threadIdx.x;
    int wave = tid >> 6, lane = tid & 63;
    int m0 = blockIdx.x * 128;
#pragma unroll
    for (int i = 0; i < 4; ++i) {
        ((float4*)sWh)[tid + i * 256] = ((const float4*)img)[tid + i * 256];
        ((float4*)sWl)[tid + i * 256] = ((const float4*)(img + 8192))[tid + i * 256];
    }
    f32x16 acc[2];
#pragma unroll
    for (int j = 0; j < 2; ++j)
#pragma unroll
        for (int q = 0; q < 16; ++q) acc[j][q] = 0.0f;

    for (int ch = 0; ch < 2; ++ch) {
#pragma unroll
        for (int p = 0; p < 8; ++p) {
            int idx = tid + p * 256;
            int r = idx >> 4;
            int kq = idx & 15;
            float4 v = make_float4(0, 0, 0, 0);
            int grow = m0 + r;
            if (grow < NN) v = *(const float4*)(A + (size_t)grow * D + ch * 64 + kq * 4);
            ushort4 h, l;
            h.x = f2bf(v.x); l.x = f2bf(v.x - bf2f(h.x));
            h.y = f2bf(v.y); l.y = f2bf(v.y - bf2f(h.y));
            h.z = f2bf(v.z); l.z = f2bf(v.z - bf2f(h.z));
            h.w = f2bf(v.w); l.w = f2bf(v.w - bf2f(h.w));
            int g = kq >> 1, half = kq & 1;
            int uidx = r * 64 + ((g ^ (r & 7)) * 8) + half * 4;
            *(ushort4*)&sAh[uidx] = h;
            *(ushort4*)&sAl[uidx] = l;
        }
        __syncthreads();
        int ra = wave * 32 + (lane & 31);
        int c0 = lane & 31, c1 = 32 + (lane & 31);
#pragma unroll
        for (int s = 0; s < 4; ++s) {
            int gg = s * 2 + (lane >> 5);
            int kg = ch * 8 + gg;
            bf16x8 ah = *(const bf16x8*)&sAh[ra * 64 + ((gg ^ (ra & 7)) * 8)];
            bf16x8 al = *(const bf16x8*)&sAl[ra * 64 + ((gg ^ (ra & 7)) * 8)];
            bf16x8 wh0 = *(const bf16x8*)&sWh[c0 * 128 + ((kg ^ (c0 & 7)) * 8)];
            bf16x8 wl0 = *(const bf16x8*)&sWl[c0 * 128 + ((kg ^ (c0 & 7)) * 8)];
            bf16x8 wh1 = *(const bf16x8*)&sWh[c1 * 128 + ((kg ^ (c1 & 7)) * 8)];
            bf16x8 wl1 = *(const bf16x8*)&sWl[c1 * 128 + ((kg ^ (c1 & 7)) * 8)];
            acc[0] = __builtin_amdgcn_mfma_f32_32x32x16_bf16(ah, wh0, acc[0], 0, 0, 0);
            acc[0] = __builtin_amdgcn_mfma_f32_32x32x16_bf16(ah, wl0, acc[0], 0, 0, 0);
            acc[0] = __builtin_amdgcn_mfma_f32_32x32x16_bf16(al, wh0, acc[0], 0, 0, 0);
            acc[1] = __builtin_amdgcn_mfma_f32_32x32x16_bf16(ah, wh1, acc[1], 0, 0, 0);
            acc[1] = __builtin_amdgcn_mfma_f32_32x32x16_bf16(ah, wl1, acc[1], 0, 0, 0);
            acc[1] = __builtin_amdgcn_mfma_f32_32x32x16_bf16(al, wh1, acc[1], 0, 0, 0);
        }
        __syncthreads();
    }
#pragma unroll
    for (int ct = 0; ct < 2; ++ct) {
        int col = ct * 32 + (lane & 31);
        if (col < NC) {
            float bb = b[col];
#pragma unroll
            for (int reg = 0; reg < 16; ++reg) {
                int row = m0 + wave * 32 + (reg & 3) + 8 * (reg >> 2) + 4 * (lane >> 5);
                if (row < NN) O[(size_t)row * NC + col] = acc[ct][reg] + bb;
            }
        }
    }
}

// ---------- fp16 helpers ----------
__device__ __forceinline__ float4 h4load(const ushort* __restrict__ T, int row, int l) {
    uint2 hv = ((const uint2*)(T + (size_t)row * D))[l];
    __half2 h0 = *(__half2*)&hv.x, h1 = *(__half2*)&hv.y;
    float2 f0 = __half22float2(h0), f1 = __half22float2(h1);
    return make_float4(f0.x, f0.y, f1.x, f1.y);
}

__device__ __forceinline__ void fma4(float4& a, float4 v, float w) {
    a.x = fmaf(v.x, w, a.x); a.y = fmaf(v.y, w, a.y);
    a.z = fmaf(v.z, w, a.z); a.w = fmaf(v.w, w, a.w);
}

// ---------- bucket pull, HALF-WAVE per dst; lane-resident srcs/wts + shfl ----------
template<int IMG>
__global__ __launch_bounds__(256) void aggregate_kernel(const ushort* __restrict__ T,
                                                        const int* __restrict__ cnt,
                                                        const int* __restrict__ srcs,
                                                        const float* __restrict__ wts,
                                                        const float* __restrict__ dinv,
                                                        const float* __restrict__ b,
                                                        float* __restrict__ out,
                                                        ushort* __restrict__ img) {
    int wid = (blockIdx.x * 256 + threadIdx.x) >> 5;   // half-wave id = dst node
    int l = threadIdx.x & 31;
    if (wid >= NN) return;
    float di = dinv[wid];
    float wself = di * di;
    float4 acc = h4load(T, wid, l);
    acc.x *= wself; acc.y *= wself; acc.z *= wself; acc.w *= wself;
    int base = wid * CAP;
    int deg = cnt[wid * CSTR]; if (deg > CAP) deg = CAP;
    int lim = deg < 32 ? deg : 32;
    int sreg = 0; float wreg = 0.0f;
    if (l < lim) { sreg = srcs[base + l]; wreg = wts[base + l]; }
    int e = 0;
    for (; e + 7 < lim; e += 8) {
        int s0 = __shfl(sreg, e + 0, 32), s1 = __shfl(sreg, e + 1, 32);
        int s2 = __shfl(sreg, e + 2, 32), s3 = __shfl(sreg, e + 3, 32);
        int s4 = __shfl(sreg, e + 4, 32), s5 = __shfl(sreg, e + 5, 32);
        int s6 = __shfl(sreg, e + 6, 32), s7 = __shfl(sreg, e + 7, 32);
        float4 v0 = h4load(T, s0, l), v1 = h4load(T, s1, l);
        float4 v2 = h4load(T, s2, l), v3 = h4load(T, s3, l);
        float4 v4 = h4load(T, s4, l), v5 = h4load(T, s5, l);
        float4 v6 = h4load(T, s6, l), v7 = h4load(T, s7, l);
        fma4(acc, v0, __shfl(wreg, e + 0, 32)); fma4(acc, v1, __shfl(wreg, e + 1, 32));
        fma4(acc, v2, __shfl(wreg, e + 2, 32)); fma4(acc, v3, __shfl(wreg, e + 3, 32));
        fma4(acc, v4, __shfl(wreg, e + 4, 32)); fma4(acc, v5, __shfl(wreg, e + 5, 32));
        fma4(acc, v6, __shfl(wreg, e + 6, 32)); fma4(acc, v7, __shfl(wreg, e + 7, 32));
    }
    for (; e + 3 < lim; e += 4) {
        int s0 = __shfl(sreg, e + 0, 32), s1 = __shfl(sreg, e + 1, 32);
        int s2 = __shfl(sreg, e + 2, 32), s3 = __shfl(sreg, e + 3, 32);
        float4 v0 = h4load(T, s0, l), v1 = h4load(T, s1, l);
        float4 v2 = h4load(T, s2, l), v3 = h4load(T, s3, l);
        fma4(acc, v0, __shfl(wreg, e + 0, 32)); fma4(acc, v1, __shfl(wreg, e + 1, 32));
        fma4(acc, v2, __shfl(wreg, e + 2, 32)); fma4(acc, v3, __shfl(wreg, e + 3, 32));
    }
    for (; e < lim; ++e) {
        fma4(acc, h4load(T, __shfl(sreg, e, 32), l), __shfl(wreg, e, 32));
    }
    for (; e < deg; ++e) {        // rare deg>32 tail
        fma4(acc, h4load(T, srcs[base + e], l), wts[base + e]);
    }
    float4 bb = ((const float4*)b)[l];
    acc.x = fmaxf(acc.x + bb.x, 0.0f);
    acc.y = fmaxf(acc.y + bb.y, 0.0f);
    acc.z = fmaxf(acc.z + bb.z, 0.0f);
    acc.w = fmaxf(acc.w + bb.w, 0.0f);
    if (IMG) {
        int tile = wid >> 7, rr = wid & 127;
        int c0 = 4 * l;
        int ch = c0 >> 6, kk = c0 & 63, g = kk >> 3;
        int idx = rr * 64 + ((g ^ (rr & 7)) * 8) + (kk & 7);
        ushort4 hh, ll;
        hh.x = f2bf(acc.x); ll.x = f2bf(acc.x - bf2f(hh.x));
        hh.y = f2bf(acc.y); ll.y = f2bf(acc.y - bf2f(hh.y));
        hh.z = f2bf(acc.z); ll.z = f2bf(acc.z - bf2f(hh.z));
        hh.w = f2bf(acc.w); ll.w = f2bf(acc.w - bf2f(hh.w));
        ushort* bimg = img + (size_t)tile * 32768;
        *(ushort4*)(bimg + (size_t)(ch * 2 + 0) * 8192 + idx) = hh;
        *(ushort4*)(bimg + (size_t)(ch * 2 + 1) * 8192 + idx) = ll;
    } else {
        ((float4*)(out + (size_t)wid * D))[l] = acc;
    }
}

extern "C" void kernel_launch(void* const* d_in, const int* in_sizes, int n_in,
                              void* d_out, int out_size, void* d_ws, size_t ws_size,
                              hipStream_t stream) {
    const float* x   = (const float*)d_in[0];
    const void*  ei  = d_in[1];
    const float* W1  = (const float*)d_in[2];
    const float* b1  = (const float*)d_in[3];
    const float* W2  = (const float*)d_in[4];
    const float* b2  = (const float*)d_in[5];
    const float* W3  = (const float*)d_in[6];
    const float* b3  = (const float*)d_in[7];
    const float* fcW = (const float*)d_in[8];
    const float* fcb = (const float*)d_in[9];

    float* out_h  = (float*)d_out;                       // [NN x 128]
    float* out_fc = out_h + (size_t)NN * D;              // [NN x 40]

    size_t off = 0;
    auto alloc = [&](size_t bytes) {
        void* p = (char*)d_ws + off;
        off += (bytes + 255) & ~(size_t)255;
        return p;
    };
    float*  dinv   = (float*) alloc((size_t)NN * 4);
    int*    cnt    = (int*)   alloc((size_t)NN * CSTR * 4);      // 3.2 MB (line-padded)
    int*    flag   = (int*)   alloc(256);
    int*    srcs   = (int*)   alloc((size_t)NN * CAP * 4);       // 12.8 MB
    float*  wts    = (float*) alloc((size_t)NN * CAP * 4);       // 12.8 MB
    ushort* bufT   = (ushort*)alloc((size_t)NN * D * 2);         // 12.8 MB
    ushort* himg   = (ushort*)alloc((size_t)NTILE * 32768 * 2);  // 25.6 MB
    ushort* wimg1  = (ushort*)alloc(32768 * 2);
    ushort* wimg2  = (ushort*)alloc(32768 * 2);
    ushort* wimg3  = (ushort*)alloc(32768 * 2);
    ushort* fcimg  = (ushort*)alloc(16384 * 2);
    (void)ws_size; (void)in_sizes; (void)n_in; (void)out_size;

    setup_prep_kernel<<<NZB + 1 + 448, 128, 0, stream>>>((int4*)cnt, (const int*)ei, flag,
                                                         W1, W2, W3, fcW,
                                                         wimg1, wimg2, wimg3, fcimg);
    fill_kernel<<<NCH * NXCD, 256, 0, stream>>>(ei, flag, cnt, srcs);
    dinv_kernel<<<NBLK, 256, 0, stream>>>(cnt, dinv);
    sort_kernel<<<(NN * 64 + 255) / 256, 256, 0, stream>>>(cnt, srcs, wts, dinv);

    int agg_grid = (NN * 32 + 255) / 256;   // half-wave per dst
    // layer 1: x (fp32) -> T -> h image
    gemm_f32_kernel<<<NTILE, 256, 0, stream>>>(x, wimg1, bufT);
    aggregate_kernel<1><<<agg_grid, 256, 0, stream>>>(bufT, cnt, srcs, wts, dinv, b1, nullptr, himg);
    // layer 2: h image -> T -> h image
    gemm_img_kernel<<<NTILE, 256, 0, stream>>>(himg, wimg2, bufT);
    aggregate_kernel<1><<<agg_grid, 256, 0, stream>>>(bufT, cnt, srcs, wts, dinv, b2, nullptr, himg);
    // layer 3: h image -> T -> fp32 h (d_out)
    gemm_img_kernel<<<NTILE, 256, 0, stream>>>(himg, wimg3, bufT);
    aggregate_kernel<0><<<agg_grid, 256, 0, stream>>>(bufT, cnt, srcs, wts, dinv, b3, out_h, nullptr);

    fc_mfma_kernel<<<NTILE, 256, 0, stream>>>(out_h, fcimg, fcb, out_fc);
}